// Round 8
// baseline (41.384 us; speedup 1.0000x reference)
//
#include <hip/hip_runtime.h>
#include <cmath>

#define PH 7
#define PW 7
#define FH 64
#define FW 64
#define CC 512
#define SCALE 0.0625f

typedef float f32x4 __attribute__((ext_vector_type(4)));

static __device__ __forceinline__ f32x4 vmax4(f32x4 a, f32x4 b) {
    f32x4 r;
    r.x = fmaxf(a.x, b.x); r.y = fmaxf(a.y, b.y);
    r.z = fmaxf(a.z, b.z); r.w = fmaxf(a.w, b.w);
    return r;
}

// ---------------------------------------------------------------------------
// Kernel 1: counting sort of ROIs by feature-space start row (64 buckets) AND
// per-ROI geometry precompute: geo[slot] = {bin_h, bin_w,
// bitcast(n | sh<<10 | sw<<17 | bidx<<24), 0}. Bin sizes use the XLA
// reciprocal-multiply form roi/7 -> roi * fl32(1/7) (proven bit-exact, R3).
// ---------------------------------------------------------------------------
__global__ __launch_bounds__(512) void sort_rois_kernel(
        const float* __restrict__ rois, int N, float4* __restrict__ geo) {
    __shared__ int base[64];
    __shared__ int cur[64];
    int t = threadIdx.x;
    if (t < 64) { base[t] = 0; cur[t] = 0; }
    __syncthreads();
    int b = -1, packed = 0;
    float bh = 0.f, bw = 0.f;
    if (t < N) {
        const float* r = rois + (size_t)t * 5;
        int bidx = (int)r[0];
        int sw = (int)rintf(r[1] * SCALE);
        int sh = (int)rintf(r[2] * SCALE);
        int ew = (int)rintf(r[3] * SCALE);
        int eh = (int)rintf(r[4] * SCALE);
        bh = fmaxf((float)(eh - sh + 1), 1.0f) * (1.0f / 7.0f);
        bw = fmaxf((float)(ew - sw + 1), 1.0f) * (1.0f / 7.0f);
        packed = t | (sh << 10) | (sw << 17) | (bidx << 24);
        b = min(max(sh, 0), FH - 1);
        atomicAdd(&base[b], 1);
    }
    __syncthreads();
    if (t == 0) {
        int acc = 0;
        for (int i = 0; i < 64; ++i) { int c = base[i]; base[i] = acc; acc += c; }
    }
    __syncthreads();
    if (t < N) {
        int pos = base[b] + atomicAdd(&cur[b], 1);
        float4 g;
        g.x = bh; g.y = bw; g.z = __int_as_float(packed); g.w = 0.f;
        geo[pos] = g;
    }
}

// ---------------------------------------------------------------------------
// Kernel 2: ONE WAVE PER BIN-ROW (sorted roi s, ph). Walks the row-band
// [hs,he) column-major across the union of the 7 bins' columns. Adjacent
// bins overlap by at most 1 column; the previous column's col-max (vLast)
// carries into the next bin's accumulator -> each feature cell of the band
// is loaded exactly once (full horizontal dedup, ~580->~400 MB logical).
// Accumulators are scalar-named registers only (no dynamic indexing).
// Per column: 2R independent dwordx4 loads (R = band height, exact
// quad/pair/single decomposition, no duplicate-pad). Geometry ops are the
// bit-exact fp32 XLA forms proven in round 3.
// ---------------------------------------------------------------------------
__global__ __launch_bounds__(256) void roi_pool_kernel(
        const float* __restrict__ feat,
        const float4* __restrict__ geo,
        float* __restrict__ out,
        int nRows) {
    // bijective XCD-chunk swizzle (HW: XCD = blockIdx % 8); 896 blocks -> each
    // XCD runs sorted ROIs [64k, 64k+64) = one L2-resident horizontal band.
    int p = blockIdx.x, nwg = gridDim.x;
    int q = nwg >> 3, rr = nwg & 7;
    int xcd = p & 7, o = p >> 3;
    int L = (xcd < rr ? xcd * (q + 1) : rr * (q + 1) + (xcd - rr) * q) + o;

    int lane = (int)threadIdx.x & 63;
    int wid = __builtin_amdgcn_readfirstlane(L * 4 + ((int)threadIdx.x >> 6));
    if (wid >= nRows) return;
    int s  = wid / 7;            // sorted roi slot
    int ph = wid - s * 7;

    float4 g = geo[s];
    float bh = g.x, bw = g.y;
    int packed = __float_as_int(g.z);
    int n    = packed & 1023;
    int sh   = (packed >> 10) & 127;
    int sw   = (packed >> 17) & 127;
    int bidx = (packed >> 24) & 255;

    int hs = min(max((int)floorf((float)ph * bh) + sh, 0), FH);
    int he = min(max((int)ceilf((float)(ph + 1) * bh) + sh, 0), FH);
    int R  = he - hs;

    float* outB = out + (size_t)(n * 49 + ph * 7) * CC + (size_t)lane * 4;
    const f32x4 zero4 = {0.f, 0.f, 0.f, 0.f};
    const f32x4 negi  = {-INFINITY, -INFINITY, -INFINITY, -INFINITY};

    if (R <= 0) {  // whole bin-row empty -> reference outputs zeros
        for (int pw = 0; pw < 7; ++pw) {
            __builtin_nontemporal_store(zero4, (f32x4*)(outB + pw * CC));
            __builtin_nontemporal_store(zero4, (f32x4*)(outB + pw * CC + 256));
        }
        return;
    }

    const float* fb = feat + (size_t)((bidx * FH + hs) * FW) * CC + (size_t)lane * 4;
    const int RS = FW * CC;      // feature row stride in floats

    f32x4 vLastA = negi, vLastB = negi;  // previous column's col-max
    int wdone = 0;               // columns loaded so far end at wdone-1

    for (int pw = 0; pw < 7; ++pw) {
        int ws = min(max((int)floorf((float)pw * bw) + sw, 0), FW);
        int we = min(max((int)ceilf((float)(pw + 1) * bw) + sw, 0), FW);
        if (we <= ws) {          // clip-empty bin (right/bottom edge ROIs)
            __builtin_nontemporal_store(zero4, (f32x4*)(outB + pw * CC));
            __builtin_nontemporal_store(zero4, (f32x4*)(outB + pw * CC + 256));
            continue;
        }
        // carry: column wdone-1 is in this bin's window iff wdone > ws
        f32x4 accA = (wdone > ws) ? vLastA : negi;
        f32x4 accB = (wdone > ws) ? vLastB : negi;
        int wbeg = max(ws, wdone);
        for (int w = wbeg; w < we; ++w) {
            const float* cb = fb + (size_t)w * CC;
            f32x4 cA = negi, cB = negi;
            int r = 0;
            for (; r + 4 <= R; r += 4) {   // 8 loads in flight
                const float* p0 = cb + (size_t)(r + 0) * RS;
                const float* p1 = cb + (size_t)(r + 1) * RS;
                const float* p2 = cb + (size_t)(r + 2) * RS;
                const float* p3 = cb + (size_t)(r + 3) * RS;
                f32x4 a0 = *(const f32x4*)p0; f32x4 b0 = *(const f32x4*)(p0 + 256);
                f32x4 a1 = *(const f32x4*)p1; f32x4 b1 = *(const f32x4*)(p1 + 256);
                f32x4 a2 = *(const f32x4*)p2; f32x4 b2 = *(const f32x4*)(p2 + 256);
                f32x4 a3 = *(const f32x4*)p3; f32x4 b3 = *(const f32x4*)(p3 + 256);
                cA = vmax4(cA, vmax4(vmax4(a0, a1), vmax4(a2, a3)));
                cB = vmax4(cB, vmax4(vmax4(b0, b1), vmax4(b2, b3)));
            }
            if (R & 2) {                    // 4 loads
                const float* p0 = cb + (size_t)(r + 0) * RS;
                const float* p1 = cb + (size_t)(r + 1) * RS;
                f32x4 a0 = *(const f32x4*)p0; f32x4 b0 = *(const f32x4*)(p0 + 256);
                f32x4 a1 = *(const f32x4*)p1; f32x4 b1 = *(const f32x4*)(p1 + 256);
                cA = vmax4(cA, vmax4(a0, a1));
                cB = vmax4(cB, vmax4(b0, b1));
                r += 2;
            }
            if (R & 1) {                    // 2 loads
                const float* p0 = cb + (size_t)r * RS;
                f32x4 a0 = *(const f32x4*)p0; f32x4 b0 = *(const f32x4*)(p0 + 256);
                cA = vmax4(cA, a0);
                cB = vmax4(cB, b0);
            }
            accA = vmax4(accA, cA);
            accB = vmax4(accB, cB);
            vLastA = cA; vLastB = cB;
        }
        wdone = we;
        __builtin_nontemporal_store(accA, (f32x4*)(outB + pw * CC));
        __builtin_nontemporal_store(accB, (f32x4*)(outB + pw * CC + 256));
    }
}

extern "C" void kernel_launch(void* const* d_in, const int* in_sizes, int n_in,
                              void* d_out, int out_size, void* d_ws, size_t ws_size,
                              hipStream_t stream) {
    const float* feat = (const float*)d_in[0];
    const float* rois = (const float*)d_in[1];
    float* out = (float*)d_out;
    float4* geo = (float4*)d_ws;           // 512 * 16B = 8KB scratch

    int N = in_sizes[1] / 5;               // 512 rois
    sort_rois_kernel<<<1, 512, 0, stream>>>(rois, N, geo);

    int nRows = N * PH;                    // 3584 bin-rows, one wave each
    int totalThreads = nRows * 64;
    int block = 256;
    int grid = (totalThreads + block - 1) / block;   // 896 (divisible by 8)
    roi_pool_kernel<<<grid, block, 0, stream>>>(feat, geo, out, nRows);
}

// Round 9
// 32.700 us; speedup vs baseline: 1.2656x; 1.2656x over previous
//
#include <hip/hip_runtime.h>
#include <cmath>

#define PH 7
#define PW 7
#define FH 64
#define FW 64
#define CC 512
#define SCALE 0.0625f

typedef float f32x4 __attribute__((ext_vector_type(4)));

static __device__ __forceinline__ f32x4 vmax4(f32x4 a, f32x4 b) {
    f32x4 r;
    r.x = fmaxf(a.x, b.x); r.y = fmaxf(a.y, b.y);
    r.z = fmaxf(a.z, b.z); r.w = fmaxf(a.w, b.w);
    return r;
}

// ---------------------------------------------------------------------------
// Kernel 1: counting sort of ROIs by feature-space start row (64 buckets) AND
// per-ROI geometry precompute: geo[slot] = {bin_h, bin_w,
// bitcast(n | sh<<10 | sw<<17 | bidx<<24), 0}. Bin sizes use the XLA
// reciprocal-multiply form roi/7 -> roi * fl32(1/7) (proven bit-exact, R3).
// ---------------------------------------------------------------------------
__global__ __launch_bounds__(512) void sort_rois_kernel(
        const float* __restrict__ rois, int N, float4* __restrict__ geo) {
    __shared__ int base[64];
    __shared__ int cur[64];
    int t = threadIdx.x;
    if (t < 64) { base[t] = 0; cur[t] = 0; }
    __syncthreads();
    int b = -1, packed = 0;
    float bh = 0.f, bw = 0.f;
    if (t < N) {
        const float* r = rois + (size_t)t * 5;
        int bidx = (int)r[0];
        int sw = (int)rintf(r[1] * SCALE);
        int sh = (int)rintf(r[2] * SCALE);
        int ew = (int)rintf(r[3] * SCALE);
        int eh = (int)rintf(r[4] * SCALE);
        bh = fmaxf((float)(eh - sh + 1), 1.0f) * (1.0f / 7.0f);
        bw = fmaxf((float)(ew - sw + 1), 1.0f) * (1.0f / 7.0f);
        packed = t | (sh << 10) | (sw << 17) | (bidx << 24);
        b = min(max(sh, 0), FH - 1);
        atomicAdd(&base[b], 1);
    }
    __syncthreads();
    if (t == 0) {
        int acc = 0;
        for (int i = 0; i < 64; ++i) { int c = base[i]; base[i] = acc; acc += c; }
    }
    __syncthreads();
    if (t < N) {
        int pos = base[b] + atomicAdd(&cur[b], 1);
        float4 g;
        g.x = bh; g.y = bw; g.z = __int_as_float(packed); g.w = 0.f;
        geo[pos] = g;
    }
}

// ---------------------------------------------------------------------------
// Kernel 2: Caffe ROI max-pool. TWO WAVES PER BIN (half = 256 channels each,
// lane owns exactly one float4): 50176 short uniform waves (~49/CU) so the
// per-wave L2-latency stall always has other resident waves to hide behind
// (round 8 proved occupancy, not bytes, is the binding constraint:
// FETCH 26->17 MB with occupancy 55->14% regressed 30->42 us).
// Sorted-ROI order + bijective XCD-chunk swizzle keep each XCD's reads in
// its private 4MB L2 (FETCH 112->26 MB, proven round 4).
// Inner loop: 8 independent dwordx4 loads in flight, exact 4/1 tails,
// no duplicate reads. Geometry = bit-exact fp32 XLA forms (round 3).
// ---------------------------------------------------------------------------
__global__ __launch_bounds__(256) void roi_pool_kernel(
        const float* __restrict__ feat,
        const float4* __restrict__ geo,
        float* __restrict__ out,
        int nBins) {
    // bijective XCD-chunk swizzle (HW: XCD = blockIdx % 8)
    int p = blockIdx.x, nwg = gridDim.x;
    int q = nwg >> 3, rr = nwg & 7;
    int xcd = p & 7, o = p >> 3;
    int L = (xcd < rr ? xcd * (q + 1) : rr * (q + 1) + (xcd - rr) * q) + o;

    int tid = L * 256 + (int)threadIdx.x;
    int wv   = tid >> 6;         // global wave id
    int lane = tid & 63;
    int bin  = wv >> 1;          // two waves per bin
    int half = wv & 1;           // channel half: [half*256, half*256+256)
    if (bin >= nBins) return;

    int s   = bin / (PH * PW);   // sorted roi slot
    int rem = bin - s * (PH * PW);
    int ph  = rem / PW;
    int pw  = rem - ph * PW;

    float4 g = geo[s];
    float bh = g.x, bw = g.y;
    int packed = __float_as_int(g.z);
    int n    = packed & 1023;
    int sh   = (packed >> 10) & 127;
    int sw   = (packed >> 17) & 127;
    int bidx = (packed >> 24) & 255;

    int hstart = min(max((int)floorf((float)ph * bh) + sh, 0), FH);
    int hend   = min(max((int)ceilf((float)(ph + 1) * bh) + sh, 0), FH);
    int wstart = min(max((int)floorf((float)pw * bw) + sw, 0), FW);
    int wend   = min(max((int)ceilf((float)(pw + 1) * bw) + sw, 0), FW);
    bool empty = (hend <= hstart) || (wend <= wstart);

    f32x4 mx = { -INFINITY, -INFINITY, -INFINITY, -INFINITY };

    if (!empty) {
        const int W = wend - wstart;
        int cells = (hend - hstart) * W;
        const float* ptr = feat + (size_t)bidx * (FH * FW * CC)
                         + (size_t)hstart * (FW * CC) + (size_t)wstart * CC
                         + (size_t)(half * 256 + lane * 4);
        const int stepWrap = (FW - W + 1) * CC;  // last col -> next row start
        int cw = W;  // cols left in current row (incl. current ptr position)

#define ADV() do { if (--cw == 0) { ptr += stepWrap; cw = W; } else ptr += CC; } while (0)

        while (cells >= 8) {     // 8 independent loads in flight
            const float* q0 = ptr; ADV();
            const float* q1 = ptr; ADV();
            const float* q2 = ptr; ADV();
            const float* q3 = ptr; ADV();
            const float* q4 = ptr; ADV();
            const float* q5 = ptr; ADV();
            const float* q6 = ptr; ADV();
            const float* q7 = ptr; ADV();
            f32x4 a0 = *(const f32x4*)q0; f32x4 a1 = *(const f32x4*)q1;
            f32x4 a2 = *(const f32x4*)q2; f32x4 a3 = *(const f32x4*)q3;
            f32x4 a4 = *(const f32x4*)q4; f32x4 a5 = *(const f32x4*)q5;
            f32x4 a6 = *(const f32x4*)q6; f32x4 a7 = *(const f32x4*)q7;
            a0 = vmax4(a0, a1); a2 = vmax4(a2, a3);
            a4 = vmax4(a4, a5); a6 = vmax4(a6, a7);
            mx = vmax4(mx, vmax4(vmax4(a0, a2), vmax4(a4, a6)));
            cells -= 8;
        }
        if (cells >= 4) {        // 4 in flight
            const float* q0 = ptr; ADV();
            const float* q1 = ptr; ADV();
            const float* q2 = ptr; ADV();
            const float* q3 = ptr; ADV();
            f32x4 a0 = *(const f32x4*)q0; f32x4 a1 = *(const f32x4*)q1;
            f32x4 a2 = *(const f32x4*)q2; f32x4 a3 = *(const f32x4*)q3;
            mx = vmax4(mx, vmax4(vmax4(a0, a1), vmax4(a2, a3)));
            cells -= 4;
        }
        while (cells > 0) {
            const float* q0 = ptr; ADV();
            mx = vmax4(mx, *(const f32x4*)q0);
            --cells;
        }
#undef ADV
    } else {
        mx = (f32x4){0.f, 0.f, 0.f, 0.f};
    }

    float* op = out + ((size_t)n * (PH * PW) + rem) * CC
              + (size_t)(half * 256 + lane * 4);
    __builtin_nontemporal_store(mx, (f32x4*)op);
}

extern "C" void kernel_launch(void* const* d_in, const int* in_sizes, int n_in,
                              void* d_out, int out_size, void* d_ws, size_t ws_size,
                              hipStream_t stream) {
    const float* feat = (const float*)d_in[0];
    const float* rois = (const float*)d_in[1];
    float* out = (float*)d_out;
    float4* geo = (float4*)d_ws;           // 512 * 16B = 8KB scratch

    int N = in_sizes[1] / 5;               // 512 rois
    sort_rois_kernel<<<1, 512, 0, stream>>>(rois, N, geo);

    int nBins = N * PH * PW;               // 25088
    int totalThreads = nBins * 2 * 64;     // two waves per bin
    int block = 256;
    int grid = (totalThreads + block - 1) / block;   // 12544 (%8 == 0)
    roi_pool_kernel<<<grid, block, 0, stream>>>(feat, geo, out, nBins);
}